// Round 4
// baseline (815.431 us; speedup 1.0000x reference)
//
#include <hip/hip_runtime.h>
#include <math.h>
#include <stdint.h>

// ---------- types ----------
typedef float  f32x4  __attribute__((ext_vector_type(4)));
typedef __bf16 bf16x8 __attribute__((ext_vector_type(8)));
typedef __bf16 bf16x4 __attribute__((ext_vector_type(4)));
typedef unsigned int u32x4 __attribute__((ext_vector_type(4)));

#define MFMA16(a, b, c) __builtin_amdgcn_mfma_f32_16x16x32_bf16(a, b, c, 0, 0, 0)

// async global->LDS, 16B per lane; LDS dest = wave-uniform base + lane*16
__device__ __forceinline__ void async16(const void* g, void* l) {
  __builtin_amdgcn_global_load_lds((__attribute__((address_space(1))) void*)g,
                                   (__attribute__((address_space(3))) void*)l,
                                   16, 0, 0);
}

// inline-asm ds_read_b128: invisible to alias analysis, so the compiler cannot
// insert its own s_waitcnt vmcnt(0) ordering vs outstanding global_load_lds
// (which was flattening the counted-vmcnt pipeline to drain0). Correctness is
// carried by the explicit vmcnt(4)/lgkmcnt(0) + sched_barrier(0) (rule #18).
__device__ __forceinline__ bf16x8 dsr16(const void* p) {
  u32x4 r;
  asm volatile("ds_read_b128 %0, %1"
               : "=v"(r)
               : "v"((__attribute__((address_space(3))) const void*)p));
  union { u32x4 u; bf16x8 b; } c;
  c.u = r;
  return c.b;
}

// ---------- elementwise f32 -> bf16 cast ----------
__global__ __launch_bounds__(256) void cast_f32_to_bf16(const float* __restrict__ in,
                                                        __bf16* __restrict__ out, int n) {
  int idx = (blockIdx.x * 256 + threadIdx.x) * 4;
  if (idx + 3 < n) {
    float4 v = *(const float4*)(in + idx);
    bf16x4 o;
    o[0] = (__bf16)v.x; o[1] = (__bf16)v.y; o[2] = (__bf16)v.z; o[3] = (__bf16)v.w;
    *(bf16x4*)(out + idx) = o;
  }
}

// ---------- YaRN rope table: (cos,sin)*concentration per (pos, d<32) ----------
__global__ __launch_bounds__(256) void rope_table_kernel(const int* __restrict__ pos_ids,
                                                         float2* __restrict__ tab, int total) {
  int idx = blockIdx.x * 256 + threadIdx.x;
  if (idx >= total) return;
  int p = idx >> 5, d = idx & 31;
  float posf = (float)pos_ids[p];
  float ex = (float)(2 * d) * (1.0f / 64.0f);
  float freq = powf(150000.0f, ex);
  float inv_scaled = 1.0f / (32.0f * freq);
  float inv_plain = 1.0f / freq;
  float lr = logf(150000.0f);
  const float TWO_PI = 6.28318530717958647692f;
  float low  = 32.0f * logf(4096.0f / (32.0f * TWO_PI)) / lr;
  float high = 32.0f * logf(4096.0f / TWO_PI) / lr;
  float ramp = ((float)d - low) / (high - low);
  ramp = fminf(fmaxf(ramp, 0.0f), 1.0f);
  float maskv = 1.0f - ramp;
  float inv_freq = inv_scaled * (1.0f - maskv) + inv_plain * maskv;
  float conc = 0.1f * logf(32.0f) + 1.0f;
  float ang = posf * inv_freq;
  float s, c;
  sincosf(ang, &s, &c);
  tab[idx] = make_float2(c * conc, s * conc);
}

// ---------- 256x256-tile 8-phase bf16 GEMM: C[M][N] = A[M][K]*B[N][K]^T + bias[N] ----------
// T2+T3+T4+T5 stack; fragment reads via inline-asm ds_read_b128 (see dsr16).
// Phases are quadrants (row-half x kh): ph1 reads a[0..3]+b[0..3], ph2 a[4..7] (B reused),
// ph3/ph4 same for kh1. Each phase:
//   asm ds_read -> stage 1 unit -> [vmcnt @ph4] -> s_barrier -> lgkmcnt(0)
//   -> sched_barrier(0) [rule 18] -> setprio(1) -> 16 MFMA -> setprio(0) -> s_barrier.
// Stage schedule per tile t: ph1:A(t+1,kh1) ph2:B(t+1,kh1) ph3:A(t+2,kh0) ph4:B(t+2,kh0),
// vmcnt(4) at ph4 only: drains everything tile t+1 needs, leaves (t+2,kh0) in flight.
// LDS chunk swizzle: position (row,c) holds global chunk c^((row>>1)&3) via pre-swizzled
// per-lane global source (LDS dest stays lane*16-linear as global_load_lds requires).
template <typename OutT, bool DO_ROPE>
__global__ __launch_bounds__(512, 2) void gemm256(const __bf16* __restrict__ A,
                                                  const __bf16* __restrict__ B,
                                                  const float* __restrict__ bias,
                                                  OutT* __restrict__ C,
                                                  const float2* __restrict__ tab,
                                                  int M, int N, int K) {
  __shared__ __align__(16) __bf16 lds_all[65536];   // 128 KiB
  __bf16* Asl = lds_all;            // 4 slots x 8192 elems
  __bf16* Bsl = lds_all + 32768;

  const int tid = threadIdx.x;
  const int wv  = tid >> 6;          // 0..7
  const int ln  = tid & 63;
  const int l16 = ln & 15;
  const int quad = ln >> 4;
  const int wr = wv >> 2;            // 0..1 -> 128-row half
  const int wc = wv & 3;             // 0..3 -> 64-col strip

  const int nTN = (N + 255) >> 8;
  int bid = (int)blockIdx.x;
  int nwg = (int)gridDim.x;
  int swz = bid;
  if ((nwg & 7) == 0) {              // bijective XCD chunking
    int cpx = nwg >> 3;
    swz = (bid & 7) * cpx + (bid >> 3);
  }
  const int brow = swz / nTN;
  const int bcol = swz % nTN;
  const int row0 = brow << 8, col0 = bcol << 8;

  // reader offsets (bf16 elems within a 16KB slot: row*32 + chunk'*8)
  const int rsw  = (l16 >> 1) & 3;
  const int aoff = (wr * 128 + l16) * 32 + ((quad ^ rsw) * 8);
  const int boff = (wc * 64 + l16) * 32 + ((quad ^ rsw) * 8);

  // stage constants: thread covers LDS chunk positions tid and 512+tid
  const int srow = tid >> 2;                         // 0..127 (+128 on 2nd load)
  const int skq  = (tid & 3) ^ ((tid >> 3) & 3);     // pre-swizzled global k-chunk

  auto stA = [&](int t_, int kh) {
    const __bf16* s = A + (size_t)(row0 + srow) * K + t_ * 64 + kh * 32 + skq * 8;
    char* d = (char*)Asl + (((2 * t_ + kh) & 3) << 14) + (wv << 10);
    async16(s, d);
    async16(s + (size_t)128 * K, d + 8192);
  };
  auto stB = [&](int t_, int kh) {
    int r0 = col0 + srow;       if (r0 > N - 1) r0 = N - 1;   // N-edge: dup last row
    int r1 = col0 + srow + 128; if (r1 > N - 1) r1 = N - 1;
    const int kb = t_ * 64 + kh * 32 + skq * 8;
    char* d = (char*)Bsl + (((2 * t_ + kh) & 3) << 14) + (wv << 10);
    async16(B + (size_t)r0 * K + kb, d);
    async16(B + (size_t)r1 * K + kb, d + 8192);
  };

  f32x4 acc[8][4];
#pragma unroll
  for (int t = 0; t < 8; t++)
#pragma unroll
    for (int u = 0; u < 4; u++) acc[t][u] = (f32x4){0.f, 0.f, 0.f, 0.f};

  const int nt = K >> 6;   // 64-wide K-tiles

  // ---- prologue: stage tiles 0 and 1 fully; leave (1,kh1) units in flight ----
  stA(0, 0); stB(0, 0); stA(0, 1); stB(0, 1);
  if (nt > 1) {
    stA(1, 0); stB(1, 0); stA(1, 1); stB(1, 1);
    asm volatile("s_waitcnt vmcnt(4)" ::: "memory");
  } else {
    asm volatile("s_waitcnt vmcnt(0)" ::: "memory");
  }
  __builtin_amdgcn_s_barrier();

#define PHASE_TAIL()                                      \
  __builtin_amdgcn_s_barrier();                           \
  asm volatile("s_waitcnt lgkmcnt(0)" ::: "memory");      \
  __builtin_amdgcn_sched_barrier(0);                      \
  __builtin_amdgcn_s_setprio(1);

#define PHASE_END()                                       \
  __builtin_amdgcn_s_setprio(0);                          \
  __builtin_amdgcn_s_barrier();

#pragma unroll 1
  for (int t = 0; t < nt; ++t) {
    const __bf16* As0 = Asl + (((2 * t) & 3) << 13);
    const __bf16* Bs0 = Bsl + (((2 * t) & 3) << 13);
    const __bf16* As1 = Asl + (((2 * t + 1) & 3) << 13);
    const __bf16* Bs1 = Bsl + (((2 * t + 1) & 3) << 13);
    bf16x8 a[4], b[4];

    // ---- phase 1: kh0, row-frags 0-3, all B ----
#pragma unroll
    for (int i = 0; i < 4; ++i) a[i] = dsr16(As0 + aoff + i * 512);
#pragma unroll
    for (int u = 0; u < 4; ++u) b[u] = dsr16(Bs0 + boff + u * 512);
    if (t >= 1 && t + 1 < nt) stA(t + 1, 1);
    PHASE_TAIL();
#pragma unroll
    for (int i = 0; i < 4; ++i)
#pragma unroll
      for (int u = 0; u < 4; ++u) acc[i][u] = MFMA16(a[i], b[u], acc[i][u]);
    PHASE_END();

    // ---- phase 2: kh0, row-frags 4-7 (B reused) ----
#pragma unroll
    for (int i = 0; i < 4; ++i) a[i] = dsr16(As0 + aoff + (4 + i) * 512);
    if (t >= 1 && t + 1 < nt) stB(t + 1, 1);
    PHASE_TAIL();
#pragma unroll
    for (int i = 0; i < 4; ++i)
#pragma unroll
      for (int u = 0; u < 4; ++u) acc[4 + i][u] = MFMA16(a[i], b[u], acc[4 + i][u]);
    PHASE_END();

    // ---- phase 3: kh1, row-frags 0-3, all B ----
#pragma unroll
    for (int i = 0; i < 4; ++i) a[i] = dsr16(As1 + aoff + i * 512);
#pragma unroll
    for (int u = 0; u < 4; ++u) b[u] = dsr16(Bs1 + boff + u * 512);
    if (t + 2 < nt) stA(t + 2, 0);
    PHASE_TAIL();
#pragma unroll
    for (int i = 0; i < 4; ++i)
#pragma unroll
      for (int u = 0; u < 4; ++u) acc[i][u] = MFMA16(a[i], b[u], acc[i][u]);
    PHASE_END();

    // ---- phase 4: kh1, row-frags 4-7 + tile-end counted sync ----
#pragma unroll
    for (int i = 0; i < 4; ++i) a[i] = dsr16(As1 + aoff + (4 + i) * 512);
    if (t + 2 < nt) {
      stB(t + 2, 0);
      asm volatile("s_waitcnt vmcnt(4)" ::: "memory");
    } else {
      asm volatile("s_waitcnt vmcnt(0)" ::: "memory");
    }
    PHASE_TAIL();
#pragma unroll
    for (int i = 0; i < 4; ++i)
#pragma unroll
      for (int u = 0; u < 4; ++u) acc[4 + i][u] = MFMA16(a[i], b[u], acc[4 + i][u]);
    PHASE_END();
  }
#undef PHASE_TAIL
#undef PHASE_END

  // ---- epilogue ----
  const int hh = (col0 + wc * 64) >> 6;   // head index of this wave's 64-col strip
  if (DO_ROPE && hh < 72) {
    const float scale = hh < 64 ? 0.125f : 1.0f;   // SM_SCALE on q only
    float bv[4];
#pragma unroll
    for (int u = 0; u < 4; u++) bv[u] = bias[col0 + wc * 64 + u * 16 + l16];
#pragma unroll
    for (int tt = 0; tt < 8; ++tt) {
      int rowb = row0 + wr * 128 + tt * 16 + quad * 4;
#pragma unroll
      for (int r = 0; r < 4; r++) {
        int row = rowb + r;
#pragma unroll
        for (int u = 0; u < 2; u++) {
          float2 cs = tab[row * 32 + u * 16 + l16];
          float x1 = acc[tt][u][r] + bv[u];
          float x2 = acc[tt][u + 2][r] + bv[u + 2];
          C[(size_t)row * N + col0 + wc * 64 + u * 16 + l16] =
              (OutT)((x1 * cs.x - x2 * cs.y) * scale);
          C[(size_t)row * N + col0 + wc * 64 + (u + 2) * 16 + l16] =
              (OutT)((x2 * cs.x + x1 * cs.y) * scale);
        }
      }
    }
  } else {
#pragma unroll
    for (int u = 0; u < 4; u++) {
      int col = col0 + wc * 64 + u * 16 + l16;
      if (col < N) {
        float bv = bias[col];
#pragma unroll
        for (int tt = 0; tt < 8; ++tt) {
          int row = row0 + wr * 128 + tt * 16 + quad * 4;
#pragma unroll
          for (int r = 0; r < 4; r++)
            C[(size_t)(row + r) * N + col] = (OutT)(acc[tt][u][r] + bv);
        }
      }
    }
  }
}

// ---------- banded attention with sinks ----------
// grid = nb(64) * kvh(8) * qhalf(2) = 1024 blocks of 256 threads (4 waves).
// K AND V staged in LDS once per block (all 8 passes reuse the same 256-key K/V block);
// K XOR-swizzled so the 16-lane column ds_read_b128 is conflict-free.
// LDS: vT 33.8KB + K 32.8KB + p 9.2KB = 75.8KB -> 2 blocks/CU.
__global__ __launch_bounds__(256) void attn_kernel(const __bf16* __restrict__ qkv,
                                                   const float* __restrict__ sinks,
                                                   __bf16* __restrict__ out) {
  __shared__ __align__(16) __bf16 vT_s[64 * 264];   // [dim][key(+pad)] swizzled
  __shared__ __align__(16) __bf16 k_s[256 * 64];    // [key][dim-chunk ^ (key&7)]
  __shared__ __align__(16) __bf16 p_s[64 * 72];     // [qrow][key-quarter(+pad)]
  const int tid = threadIdx.x;
  const int bh = blockIdx.x >> 1;
  const int qh = blockIdx.x & 1;
  const int b = bh >> 3;
  const int h = bh & 7;
  const int wv = tid >> 6;
  const int ln = tid & 63;
  const int l16 = ln & 15;
  const int quad = ln >> 4;

  // ---- stage K and V^T (256 keys x 64 dims), zeros for the (nonexistent) block -1 ----
  for (int c = tid; c < 2048; c += 256) {
    int key = c >> 3, dc = c & 7;
    int pos = b * 128 + key - 128;
    bf16x8 vv = {}, kk = {};
    if (pos >= 0) {
      const __bf16* base = qkv + (size_t)pos * 5120 + h * 64 + dc * 8;
      kk = *(const bf16x8*)(base + 4096);
      vv = *(const bf16x8*)(base + 4608);
    }
    int keysw = key ^ ((dc & 3) << 3);   // chunk swizzle: breaks 16-way b16-write conflict
#pragma unroll
    for (int l2 = 0; l2 < 8; l2++)
      vT_s[(dc * 8 + l2) * 264 + keysw] = vv[l2];
    *(bf16x8*)&k_s[key * 64 + ((dc ^ (key & 7)) * 8)] = kk;
  }
  __syncthreads();

#pragma unroll 1
  for (int pass = 0; pass < 8; pass++) {
    int g = qh * 4 + (pass >> 1);
    int i0 = (pass & 1) * 64 + wv * 16;          // position-in-block of this wave's 16 rows
    int head = h * 8 + g;
    float sink = sinks[head];

    size_t qbase = (size_t)(b * 128 + i0 + l16) * 5120 + head * 64;
    bf16x8 aq0 = *(const bf16x8*)(qkv + qbase + quad * 8);
    bf16x8 aq1 = *(const bf16x8*)(qkv + qbase + 32 + quad * 8);

    // ---- scores: 16 rows x 256 keys in C-layout regs; K from LDS ----
    f32x4 sc[16];
    const int sw0 = (quad ^ (l16 & 7)) * 8;
#pragma unroll
    for (int ct = 0; ct < 16; ct++) {
      const __bf16* kp = &k_s[(ct * 16 + l16) * 64];
      bf16x8 kb0 = *(const bf16x8*)(kp + sw0);
      bf16x8 kb1 = *(const bf16x8*)(kp + (sw0 ^ 32));
      f32x4 z = (f32x4){0.f, 0.f, 0.f, 0.f};
      __builtin_amdgcn_s_setprio(1);
      z = MFMA16(aq0, kb0, z);
      z = MFMA16(aq1, kb1, z);
      __builtin_amdgcn_s_setprio(0);
      sc[ct] = z;
    }

    // ---- mask + row max ----
    float mx[4] = {-INFINITY, -INFINITY, -INFINITY, -INFINITY};
#pragma unroll
    for (int ct = 0; ct < 16; ct++) {
      int j = ct * 16 + l16;
#pragma unroll
      for (int r = 0; r < 4; r++) {
        int i = i0 + quad * 4 + r;
        bool valid = (j >= i + 1) && (j <= i + 128) && (b > 0 || j >= 128);
        float s = valid ? sc[ct][r] : -INFINITY;
        sc[ct][r] = s;
        mx[r] = fmaxf(mx[r], s);
      }
    }
#pragma unroll
    for (int off = 1; off < 16; off <<= 1)
#pragma unroll
      for (int r = 0; r < 4; r++)
        mx[r] = fmaxf(mx[r], __shfl_xor(mx[r], off));
#pragma unroll
    for (int r = 0; r < 4; r++) mx[r] = fmaxf(mx[r], sink);

    // ---- exp + row sum (division deferred to epilogue) ----
    float sum[4] = {0.f, 0.f, 0.f, 0.f};
#pragma unroll
    for (int ct = 0; ct < 16; ct++)
#pragma unroll
      for (int r = 0; r < 4; r++) {
        float e = __expf(sc[ct][r] - mx[r]);
        sc[ct][r] = e;
        sum[r] += e;
      }
#pragma unroll
    for (int off = 1; off < 16; off <<= 1)
#pragma unroll
      for (int r = 0; r < 4; r++)
        sum[r] += __shfl_xor(sum[r], off);

    // ---- PV: P through LDS (C-layout -> A-layout), four 64-key quarters ----
    f32x4 o[4];
#pragma unroll
    for (int dt = 0; dt < 4; dt++) o[dt] = (f32x4){0.f, 0.f, 0.f, 0.f};
#pragma unroll
    for (int q = 0; q < 4; q++) {
#pragma unroll
      for (int ct = 0; ct < 4; ct++)
#pragma unroll
        for (int r = 0; r < 4; r++)
          p_s[(wv * 16 + quad * 4 + r) * 72 + ct * 16 + l16] = (__bf16)sc[q * 4 + ct][r];
#pragma unroll
      for (int ks = 0; ks < 2; ks++) {
        bf16x8 pa = *(const bf16x8*)&p_s[(wv * 16 + l16) * 72 + ks * 32 + quad * 8];
        __builtin_amdgcn_s_setprio(1);
#pragma unroll
        for (int dt = 0; dt < 4; dt++) {
          int kk = q * 64 + ks * 32 + quad * 8;
          int sw = ((dt * 2 + (l16 >> 3)) & 3) << 3;
          bf16x8 vb = *(const bf16x8*)&vT_s[(dt * 16 + l16) * 264 + (kk ^ sw)];
          o[dt] = MFMA16(pa, vb, o[dt]);
        }
        __builtin_amdgcn_s_setprio(0);
      }
    }

    // ---- epilogue: scale by 1/denom (denom = sum + exp(sink - m)), store bf16 ----
#pragma unroll
    for (int r = 0; r < 4; r++) {
      float rd = 1.0f / (sum[r] + __expf(sink - mx[r]));
      int posn = b * 128 + i0 + quad * 4 + r;
      size_t obase = (size_t)posn * 4096 + head * 64;
#pragma unroll
      for (int dt = 0; dt < 4; dt++)
        out[obase + dt * 16 + l16] = (__bf16)(o[dt][r] * rd);
    }
  }
}

// ---------- launch ----------
extern "C" void kernel_launch(void* const* d_in, const int* in_sizes, int n_in,
                              void* d_out, int out_size, void* d_ws, size_t ws_size,
                              hipStream_t stream) {
  (void)in_sizes; (void)n_in; (void)out_size; (void)ws_size;
  const float* hs     = (const float*)d_in[0];
  const int*   pos    = (const int*)d_in[1];
  const float* qkv_w  = (const float*)d_in[2];
  const float* qkv_b  = (const float*)d_in[3];
  const float* o_w    = (const float*)d_in[4];
  const float* o_b    = (const float*)d_in[5];
  const float* sinks  = (const float*)d_in[6];
  float* outp = (float*)d_out;   // reference output dtype is FLOAT32
  char* ws = (char*)d_ws;

  // workspace layout (phase-aliased), total 180,486,144 bytes:
  //   [0, 83.9M)        qkv bf16 [8192][5120] (q,k roped in GEMM1 epilogue)
  //   [83.9M, 151.0M)   phase1: hs bf16 (47.2M) + rope table (2M @131.1M)
  //                     phase2: attention out bf16 [8192][4096] (67.1M)
  //   [151.0M, 180.5M)  qkv_w bf16, then (after GEMM1) o_w bf16
  const size_t O_QKV = 0;
  const size_t O_ATT = 83886080;
  const size_t O_TAB = 131072000;
  const size_t O_W   = 150994944;
  __bf16* qkvb = (__bf16*)(ws + O_QKV);
  __bf16* hsb  = (__bf16*)(ws + O_ATT);
  __bf16* attn = (__bf16*)(ws + O_ATT);
  float2* tab  = (float2*)(ws + O_TAB);
  __bf16* wb   = (__bf16*)(ws + O_W);

  cast_f32_to_bf16<<<23040, 256, 0, stream>>>(hs, hsb, 8192 * 2880);
  cast_f32_to_bf16<<<14400, 256, 0, stream>>>(qkv_w, wb, 5120 * 2880);
  rope_table_kernel<<<1024, 256, 0, stream>>>(pos, tab, 8192 * 32);
  // GEMM1: M=8192, N=5120, K=2880 -> 32x20 = 640 blocks (45 K-tiles)
  gemm256<__bf16, true><<<640, 512, 0, stream>>>(hsb, wb, qkv_b, qkvb, tab,
                                                 8192, 5120, 2880);
  cast_f32_to_bf16<<<11520, 256, 0, stream>>>(o_w, wb, 2880 * 4096);
  attn_kernel<<<1024, 256, 0, stream>>>(qkvb, sinks, attn);
  // GEMM2: M=8192, N=2880, K=4096 -> 32x12 = 384 blocks (64 K-tiles)
  gemm256<float, false><<<384, 512, 0, stream>>>(attn, wb, o_b, outp, nullptr,
                                                 8192, 2880, 4096);
}

// Round 5
// 800.173 us; speedup vs baseline: 1.0191x; 1.0191x over previous
//
#include <hip/hip_runtime.h>
#include <math.h>
#include <stdint.h>

// ---------- types ----------
typedef float  f32x4  __attribute__((ext_vector_type(4)));
typedef __bf16 bf16x8 __attribute__((ext_vector_type(8)));
typedef __bf16 bf16x4 __attribute__((ext_vector_type(4)));
typedef unsigned int u32x4 __attribute__((ext_vector_type(4)));

#define MFMA16(a, b, c) __builtin_amdgcn_mfma_f32_16x16x32_bf16(a, b, c, 0, 0, 0)

// async global->LDS, 16B per lane; LDS dest = wave-uniform base + lane*16
__device__ __forceinline__ void async16(const void* g, void* l) {
  __builtin_amdgcn_global_load_lds((__attribute__((address_space(1))) void*)g,
                                   (__attribute__((address_space(3))) void*)l,
                                   16, 0, 0);
}

// inline-asm ds_read_b128: invisible to alias analysis (no compiler-inserted
// drains vs outstanding global_load_lds). Ordering carried by explicit counted
// vmcnt/lgkmcnt + sched_barrier(0) per rule #18.
__device__ __forceinline__ bf16x8 dsr16(const void* p) {
  u32x4 r;
  asm volatile("ds_read_b128 %0, %1"
               : "=v"(r)
               : "v"((__attribute__((address_space(3))) const void*)p));
  union { u32x4 u; bf16x8 b; } c;
  c.u = r;
  return c.b;
}

// ---------- elementwise f32 -> bf16 cast ----------
__global__ __launch_bounds__(256) void cast_f32_to_bf16(const float* __restrict__ in,
                                                        __bf16* __restrict__ out, int n) {
  int idx = (blockIdx.x * 256 + threadIdx.x) * 4;
  if (idx + 3 < n) {
    float4 v = *(const float4*)(in + idx);
    bf16x4 o;
    o[0] = (__bf16)v.x; o[1] = (__bf16)v.y; o[2] = (__bf16)v.z; o[3] = (__bf16)v.w;
    *(bf16x4*)(out + idx) = o;
  }
}

// ---------- YaRN rope table: (cos,sin)*concentration per (pos, d<32) ----------
__global__ __launch_bounds__(256) void rope_table_kernel(const int* __restrict__ pos_ids,
                                                         float2* __restrict__ tab, int total) {
  int idx = blockIdx.x * 256 + threadIdx.x;
  if (idx >= total) return;
  int p = idx >> 5, d = idx & 31;
  float posf = (float)pos_ids[p];
  float ex = (float)(2 * d) * (1.0f / 64.0f);
  float freq = powf(150000.0f, ex);
  float inv_scaled = 1.0f / (32.0f * freq);
  float inv_plain = 1.0f / freq;
  float lr = logf(150000.0f);
  const float TWO_PI = 6.28318530717958647692f;
  float low  = 32.0f * logf(4096.0f / (32.0f * TWO_PI)) / lr;
  float high = 32.0f * logf(4096.0f / TWO_PI) / lr;
  float ramp = ((float)d - low) / (high - low);
  ramp = fminf(fmaxf(ramp, 0.0f), 1.0f);
  float maskv = 1.0f - ramp;
  float inv_freq = inv_scaled * (1.0f - maskv) + inv_plain * maskv;
  float conc = 0.1f * logf(32.0f) + 1.0f;
  float ang = posf * inv_freq;
  float s, c;
  sincosf(ang, &s, &c);
  tab[idx] = make_float2(c * conc, s * conc);
}

// ---------- 256x256-tile pipelined bf16 GEMM: C[M][N] = A[M][K]*B[N][K]^T + bias[N] ----------
// 4 phases per 64-K tile; LDS reads are PIPELINED ONE PHASE AHEAD into alternate
// register banks (a0/a1, bb0/bb1) so the LDS pipe runs concurrently with the MFMA
// cluster; each phase waits lgkmcnt(#reads-just-issued) — draining exactly the
// bank it is about to consume (DS ops complete in-order per wave).
// One barrier per phase. vmcnt AFTER the MFMA cluster (publication only needs to
// precede the end barrier): vmcnt(6)@ph3 publishes (t+1,kh0), vmcnt(4)@ph4
// publishes (t+1,kh1); adaptive (4/0) when tail stages are skipped.
// Stage schedule per tile t: ph1:A(t+1,kh1) ph2:B(t+1,kh1) ph3:A(t+2,kh0) ph4:B(t+2,kh0).
// Slot rotation (2t+kh)&3; WAR audit: a slot's last reads retire (own-wave lgkm)
// >=1 barrier before any re-stage of that slot.
// LDS chunk swizzle: position (row,c) holds global chunk c^((row>>1)&3) via
// pre-swizzled per-lane global source (LDS dest lane*16-linear per global_load_lds).
template <typename OutT, bool DO_ROPE>
__global__ __launch_bounds__(512, 2) void gemm256(const __bf16* __restrict__ A,
                                                  const __bf16* __restrict__ B,
                                                  const float* __restrict__ bias,
                                                  OutT* __restrict__ C,
                                                  const float2* __restrict__ tab,
                                                  int M, int N, int K) {
  __shared__ __align__(16) __bf16 lds_all[65536];   // 128 KiB
  __bf16* Asl = lds_all;            // 4 slots x 8192 elems
  __bf16* Bsl = lds_all + 32768;

  const int tid = threadIdx.x;
  const int wv  = tid >> 6;          // 0..7
  const int ln  = tid & 63;
  const int l16 = ln & 15;
  const int quad = ln >> 4;
  const int wr = wv >> 2;            // 0..1 -> 128-row half
  const int wc = wv & 3;             // 0..3 -> 64-col strip

  const int nTN = (N + 255) >> 8;
  int bid = (int)blockIdx.x;
  int nwg = (int)gridDim.x;
  int swz = bid;
  if ((nwg & 7) == 0) {              // bijective XCD chunking
    int cpx = nwg >> 3;
    swz = (bid & 7) * cpx + (bid >> 3);
  }
  const int brow = swz / nTN;
  const int bcol = swz % nTN;
  const int row0 = brow << 8, col0 = bcol << 8;

  // reader offsets (bf16 elems within a 16KB slot: row*32 + chunk'*8)
  const int rsw  = (l16 >> 1) & 3;
  const int aoff = (wr * 128 + l16) * 32 + ((quad ^ rsw) * 8);
  const int boff = (wc * 64 + l16) * 32 + ((quad ^ rsw) * 8);

  // stage constants: thread covers LDS chunk positions tid and 512+tid
  const int srow = tid >> 2;                         // 0..127 (+128 on 2nd load)
  const int skq  = (tid & 3) ^ ((tid >> 3) & 3);     // pre-swizzled global k-chunk

  auto stA = [&](int t_, int kh) {
    const __bf16* s = A + (size_t)(row0 + srow) * K + t_ * 64 + kh * 32 + skq * 8;
    char* d = (char*)Asl + (((2 * t_ + kh) & 3) << 14) + (wv << 10);
    async16(s, d);
    async16(s + (size_t)128 * K, d + 8192);
  };
  auto stB = [&](int t_, int kh) {
    int r0 = col0 + srow;       if (r0 > N - 1) r0 = N - 1;   // N-edge: dup last row
    int r1 = col0 + srow + 128; if (r1 > N - 1) r1 = N - 1;
    const int kb = t_ * 64 + kh * 32 + skq * 8;
    char* d = (char*)Bsl + (((2 * t_ + kh) & 3) << 14) + (wv << 10);
    async16(B + (size_t)r0 * K + kb, d);
    async16(B + (size_t)r1 * K + kb, d + 8192);
  };

  f32x4 acc[8][4];
#pragma unroll
  for (int t = 0; t < 8; t++)
#pragma unroll
    for (int u = 0; u < 4; u++) acc[t][u] = (f32x4){0.f, 0.f, 0.f, 0.f};

  const int nt = K >> 6;   // 64-wide K-tiles

  // ---- prologue: stage t0 fully + t1-kh0; publish t0; leave (1,kh0) in flight ----
  stA(0, 0); stB(0, 0); stA(0, 1); stB(0, 1);
  if (nt > 1) {
    stA(1, 0); stB(1, 0);
    asm volatile("s_waitcnt vmcnt(4)" ::: "memory");
  } else {
    asm volatile("s_waitcnt vmcnt(0)" ::: "memory");
  }
  __builtin_amdgcn_s_barrier();

  bf16x8 a0[4], a1[4], bb0[4], bb1[4];
  // pre-issue ph1 reads of t0 (slot 0): a03(kh0), b03(kh0)
#pragma unroll
  for (int i = 0; i < 4; ++i) a0[i] = dsr16(Asl + aoff + i * 512);
#pragma unroll
  for (int u = 0; u < 4; ++u) bb0[u] = dsr16(Bsl + boff + u * 512);

#pragma unroll 1
  for (int t = 0; t < nt; ++t) {
    const __bf16* As0 = Asl + (((2 * t) & 3) << 13);
    const __bf16* Bs0 = Bsl + (((2 * t) & 3) << 13);
    const __bf16* As1 = Asl + (((2 * t + 1) & 3) << 13);
    const __bf16* Bs1 = Bsl + (((2 * t + 1) & 3) << 13);
    const __bf16* AsN = Asl + (((2 * t + 2) & 3) << 13);
    const __bf16* BsN = Bsl + (((2 * t + 2) & 3) << 13);
    const bool st1 = (t + 1 < nt);
    const bool st2 = (t + 2 < nt);

    // ---- ph1: MFMA kh0 rows0-3 (a0 x bb0); prefetch a47(kh0)->a1 ----
    if (st1) stA(t + 1, 1);
#pragma unroll
    for (int i = 0; i < 4; ++i) a1[i] = dsr16(As0 + aoff + (4 + i) * 512);
    asm volatile("s_waitcnt lgkmcnt(4)" ::: "memory");
    __builtin_amdgcn_sched_barrier(0);
    __builtin_amdgcn_s_setprio(1);
#pragma unroll
    for (int i = 0; i < 4; ++i)
#pragma unroll
      for (int u = 0; u < 4; ++u) acc[i][u] = MFMA16(a0[i], bb0[u], acc[i][u]);
    __builtin_amdgcn_s_setprio(0);
    __builtin_amdgcn_s_barrier();

    // ---- ph2: MFMA kh0 rows4-7 (a1 x bb0); prefetch a03(kh1)->a0, b(kh1)->bb1 ----
    if (st1) stB(t + 1, 1);
#pragma unroll
    for (int i = 0; i < 4; ++i) a0[i] = dsr16(As1 + aoff + i * 512);
#pragma unroll
    for (int u = 0; u < 4; ++u) bb1[u] = dsr16(Bs1 + boff + u * 512);
    asm volatile("s_waitcnt lgkmcnt(8)" ::: "memory");
    __builtin_amdgcn_sched_barrier(0);
    __builtin_amdgcn_s_setprio(1);
#pragma unroll
    for (int i = 0; i < 4; ++i)
#pragma unroll
      for (int u = 0; u < 4; ++u) acc[4 + i][u] = MFMA16(a1[i], bb0[u], acc[4 + i][u]);
    __builtin_amdgcn_s_setprio(0);
    __builtin_amdgcn_s_barrier();

    // ---- ph3: MFMA kh1 rows0-3 (a0 x bb1); prefetch a47(kh1)->a1; publish (t+1,kh0) ----
    if (st2) stA(t + 2, 0);
#pragma unroll
    for (int i = 0; i < 4; ++i) a1[i] = dsr16(As1 + aoff + (4 + i) * 512);
    asm volatile("s_waitcnt lgkmcnt(4)" ::: "memory");
    __builtin_amdgcn_sched_barrier(0);
    __builtin_amdgcn_s_setprio(1);
#pragma unroll
    for (int i = 0; i < 4; ++i)
#pragma unroll
      for (int u = 0; u < 4; ++u) acc[i][u] = MFMA16(a0[i], bb1[u], acc[i][u]);
    __builtin_amdgcn_s_setprio(0);
    if (st2) { asm volatile("s_waitcnt vmcnt(6)" ::: "memory"); }
    else     { asm volatile("s_waitcnt vmcnt(4)" ::: "memory"); }
    __builtin_amdgcn_s_barrier();

    // ---- ph4: MFMA kh1 rows4-7 (a1 x bb1); prefetch next a03/b03; publish (t+1,kh1) ----
    if (st2) stB(t + 2, 0);
    if (st1) {
#pragma unroll
      for (int i = 0; i < 4; ++i) a0[i] = dsr16(AsN + aoff + i * 512);
#pragma unroll
      for (int u = 0; u < 4; ++u) bb0[u] = dsr16(BsN + boff + u * 512);
      asm volatile("s_waitcnt lgkmcnt(8)" ::: "memory");
    } else {
      asm volatile("s_waitcnt lgkmcnt(0)" ::: "memory");
    }
    __builtin_amdgcn_sched_barrier(0);
    __builtin_amdgcn_s_setprio(1);
#pragma unroll
    for (int i = 0; i < 4; ++i)
#pragma unroll
      for (int u = 0; u < 4; ++u) acc[4 + i][u] = MFMA16(a1[i], bb1[u], acc[4 + i][u]);
    __builtin_amdgcn_s_setprio(0);
    if (st2) { asm volatile("s_waitcnt vmcnt(4)" ::: "memory"); }
    else     { asm volatile("s_waitcnt vmcnt(0)" ::: "memory"); }
    __builtin_amdgcn_s_barrier();
  }

  // ---- epilogue ----
  const int hh = (col0 + wc * 64) >> 6;   // head index of this wave's 64-col strip
  if (DO_ROPE && hh < 72) {
    const float scale = hh < 64 ? 0.125f : 1.0f;   // SM_SCALE on q only
    float bv[4];
#pragma unroll
    for (int u = 0; u < 4; u++) bv[u] = bias[col0 + wc * 64 + u * 16 + l16];
#pragma unroll
    for (int tt = 0; tt < 8; ++tt) {
      int rowb = row0 + wr * 128 + tt * 16 + quad * 4;
#pragma unroll
      for (int r = 0; r < 4; r++) {
        int row = rowb + r;
#pragma unroll
        for (int u = 0; u < 2; u++) {
          float2 cs = tab[row * 32 + u * 16 + l16];
          float x1 = acc[tt][u][r] + bv[u];
          float x2 = acc[tt][u + 2][r] + bv[u + 2];
          C[(size_t)row * N + col0 + wc * 64 + u * 16 + l16] =
              (OutT)((x1 * cs.x - x2 * cs.y) * scale);
          C[(size_t)row * N + col0 + wc * 64 + (u + 2) * 16 + l16] =
              (OutT)((x2 * cs.x + x1 * cs.y) * scale);
        }
      }
    }
  } else {
#pragma unroll
    for (int u = 0; u < 4; u++) {
      int col = col0 + wc * 64 + u * 16 + l16;
      if (col < N) {
        float bv = bias[col];
#pragma unroll
        for (int tt = 0; tt < 8; ++tt) {
          int row = row0 + wr * 128 + tt * 16 + quad * 4;
#pragma unroll
          for (int r = 0; r < 4; r++)
            C[(size_t)(row + r) * N + col] = (OutT)(acc[tt][u][r] + bv);
        }
      }
    }
  }
}

// ---------- banded attention with sinks ----------
// grid = nb(64) * kvh(8) * qhalf(2) = 1024 blocks of 256 threads (4 waves).
// K AND V staged in LDS once per block (all 8 passes reuse the same 256-key K/V block);
// K XOR-swizzled so the 16-lane column ds_read_b128 is conflict-free.
// LDS: vT 33.8KB + K 32.8KB + p 9.2KB = 75.8KB -> 2 blocks/CU.
__global__ __launch_bounds__(256) void attn_kernel(const __bf16* __restrict__ qkv,
                                                   const float* __restrict__ sinks,
                                                   __bf16* __restrict__ out) {
  __shared__ __align__(16) __bf16 vT_s[64 * 264];   // [dim][key(+pad)] swizzled
  __shared__ __align__(16) __bf16 k_s[256 * 64];    // [key][dim-chunk ^ (key&7)]
  __shared__ __align__(16) __bf16 p_s[64 * 72];     // [qrow][key-quarter(+pad)]
  const int tid = threadIdx.x;
  const int bh = blockIdx.x >> 1;
  const int qh = blockIdx.x & 1;
  const int b = bh >> 3;
  const int h = bh & 7;
  const int wv = tid >> 6;
  const int ln = tid & 63;
  const int l16 = ln & 15;
  const int quad = ln >> 4;

  // ---- stage K and V^T (256 keys x 64 dims), zeros for the (nonexistent) block -1 ----
  for (int c = tid; c < 2048; c += 256) {
    int key = c >> 3, dc = c & 7;
    int pos = b * 128 + key - 128;
    bf16x8 vv = {}, kk = {};
    if (pos >= 0) {
      const __bf16* base = qkv + (size_t)pos * 5120 + h * 64 + dc * 8;
      kk = *(const bf16x8*)(base + 4096);
      vv = *(const bf16x8*)(base + 4608);
    }
    int keysw = key ^ ((dc & 3) << 3);   // chunk swizzle: breaks 16-way b16-write conflict
#pragma unroll
    for (int l2 = 0; l2 < 8; l2++)
      vT_s[(dc * 8 + l2) * 264 + keysw] = vv[l2];
    *(bf16x8*)&k_s[key * 64 + ((dc ^ (key & 7)) * 8)] = kk;
  }
  __syncthreads();

#pragma unroll 1
  for (int pass = 0; pass < 8; pass++) {
    int g = qh * 4 + (pass >> 1);
    int i0 = (pass & 1) * 64 + wv * 16;          // position-in-block of this wave's 16 rows
    int head = h * 8 + g;
    float sink = sinks[head];

    size_t qbase = (size_t)(b * 128 + i0 + l16) * 5120 + head * 64;
    bf16x8 aq0 = *(const bf16x8*)(qkv + qbase + quad * 8);
    bf16x8 aq1 = *(const bf16x8*)(qkv + qbase + 32 + quad * 8);

    // ---- scores: 16 rows x 256 keys in C-layout regs; K from LDS ----
    f32x4 sc[16];
    const int sw0 = (quad ^ (l16 & 7)) * 8;
#pragma unroll
    for (int ct = 0; ct < 16; ct++) {
      const __bf16* kp = &k_s[(ct * 16 + l16) * 64];
      bf16x8 kb0 = *(const bf16x8*)(kp + sw0);
      bf16x8 kb1 = *(const bf16x8*)(kp + (sw0 ^ 32));
      f32x4 z = (f32x4){0.f, 0.f, 0.f, 0.f};
      __builtin_amdgcn_s_setprio(1);
      z = MFMA16(aq0, kb0, z);
      z = MFMA16(aq1, kb1, z);
      __builtin_amdgcn_s_setprio(0);
      sc[ct] = z;
    }

    // ---- mask + row max ----
    float mx[4] = {-INFINITY, -INFINITY, -INFINITY, -INFINITY};
#pragma unroll
    for (int ct = 0; ct < 16; ct++) {
      int j = ct * 16 + l16;
#pragma unroll
      for (int r = 0; r < 4; r++) {
        int i = i0 + quad * 4 + r;
        bool valid = (j >= i + 1) && (j <= i + 128) && (b > 0 || j >= 128);
        float s = valid ? sc[ct][r] : -INFINITY;
        sc[ct][r] = s;
        mx[r] = fmaxf(mx[r], s);
      }
    }
#pragma unroll
    for (int off = 1; off < 16; off <<= 1)
#pragma unroll
      for (int r = 0; r < 4; r++)
        mx[r] = fmaxf(mx[r], __shfl_xor(mx[r], off));
#pragma unroll
    for (int r = 0; r < 4; r++) mx[r] = fmaxf(mx[r], sink);

    // ---- exp + row sum (division deferred to epilogue) ----
    float sum[4] = {0.f, 0.f, 0.f, 0.f};
#pragma unroll
    for (int ct = 0; ct < 16; ct++)
#pragma unroll
      for (int r = 0; r < 4; r++) {
        float e = __expf(sc[ct][r] - mx[r]);
        sc[ct][r] = e;
        sum[r] += e;
      }
#pragma unroll
    for (int off = 1; off < 16; off <<= 1)
#pragma unroll
      for (int r = 0; r < 4; r++)
        sum[r] += __shfl_xor(sum[r], off);

    // ---- PV: P through LDS (C-layout -> A-layout), four 64-key quarters ----
    f32x4 o[4];
#pragma unroll
    for (int dt = 0; dt < 4; dt++) o[dt] = (f32x4){0.f, 0.f, 0.f, 0.f};
#pragma unroll
    for (int q = 0; q < 4; q++) {
#pragma unroll
      for (int ct = 0; ct < 4; ct++)
#pragma unroll
        for (int r = 0; r < 4; r++)
          p_s[(wv * 16 + quad * 4 + r) * 72 + ct * 16 + l16] = (__bf16)sc[q * 4 + ct][r];
#pragma unroll
      for (int ks = 0; ks < 2; ks++) {
        bf16x8 pa = *(const bf16x8*)&p_s[(wv * 16 + l16) * 72 + ks * 32 + quad * 8];
        __builtin_amdgcn_s_setprio(1);
#pragma unroll
        for (int dt = 0; dt < 4; dt++) {
          int kk = q * 64 + ks * 32 + quad * 8;
          int sw = ((dt * 2 + (l16 >> 3)) & 3) << 3;
          bf16x8 vb = *(const bf16x8*)&vT_s[(dt * 16 + l16) * 264 + (kk ^ sw)];
          o[dt] = MFMA16(pa, vb, o[dt]);
        }
        __builtin_amdgcn_s_setprio(0);
      }
    }

    // ---- epilogue: scale by 1/denom (denom = sum + exp(sink - m)), store bf16 ----
#pragma unroll
    for (int r = 0; r < 4; r++) {
      float rd = 1.0f / (sum[r] + __expf(sink - mx[r]));
      int posn = b * 128 + i0 + quad * 4 + r;
      size_t obase = (size_t)posn * 4096 + head * 64;
#pragma unroll
      for (int dt = 0; dt < 4; dt++)
        out[obase + dt * 16 + l16] = (__bf16)(o[dt][r] * rd);
    }
  }
}

// ---------- launch ----------
extern "C" void kernel_launch(void* const* d_in, const int* in_sizes, int n_in,
                              void* d_out, int out_size, void* d_ws, size_t ws_size,
                              hipStream_t stream) {
  (void)in_sizes; (void)n_in; (void)out_size; (void)ws_size;
  const float* hs     = (const float*)d_in[0];
  const int*   pos    = (const int*)d_in[1];
  const float* qkv_w  = (const float*)d_in[2];
  const float* qkv_b  = (const float*)d_in[3];
  const float* o_w    = (const float*)d_in[4];
  const float* o_b    = (const float*)d_in[5];
  const float* sinks  = (const float*)d_in[6];
  float* outp = (float*)d_out;   // reference output dtype is FLOAT32
  char* ws = (char*)d_ws;

  // workspace layout (phase-aliased), total 180,486,144 bytes:
  //   [0, 83.9M)        qkv bf16 [8192][5120] (q,k roped in GEMM1 epilogue)
  //   [83.9M, 151.0M)   phase1: hs bf16 (47.2M) + rope table (2M @131.1M)
  //                     phase2: attention out bf16 [8192][4096] (67.1M)
  //   [151.0M, 180.5M)  qkv_w bf16, then (after GEMM1) o_w bf16
  const size_t O_QKV = 0;
  const size_t O_ATT = 83886080;
  const size_t O_TAB = 131072000;
  const size_t O_W   = 150994944;
  __bf16* qkvb = (__bf16*)(ws + O_QKV);
  __bf16* hsb  = (__bf16*)(ws + O_ATT);
  __bf16* attn = (__bf16*)(ws + O_ATT);
  float2* tab  = (float2*)(ws + O_TAB);
  __bf16* wb   = (__bf16*)(ws + O_W);

  cast_f32_to_bf16<<<23040, 256, 0, stream>>>(hs, hsb, 8192 * 2880);
  cast_f32_to_bf16<<<14400, 256, 0, stream>>>(qkv_w, wb, 5120 * 2880);
  rope_table_kernel<<<1024, 256, 0, stream>>>(pos, tab, 8192 * 32);
  // GEMM1: M=8192, N=5120, K=2880 -> 32x20 = 640 blocks (45 K-tiles)
  gemm256<__bf16, true><<<640, 512, 0, stream>>>(hsb, wb, qkv_b, qkvb, tab,
                                                 8192, 5120, 2880);
  cast_f32_to_bf16<<<11520, 256, 0, stream>>>(o_w, wb, 2880 * 4096);
  attn_kernel<<<1024, 256, 0, stream>>>(qkvb, sinks, attn);
  // GEMM2: M=8192, N=2880, K=4096 -> 32x12 = 384 blocks (64 K-tiles)
  gemm256<float, false><<<384, 512, 0, stream>>>(attn, wb, o_b, outp, nullptr,
                                                 8192, 2880, 4096);
}